// Round 1
// baseline (64.812 us; speedup 1.0000x reference)
//
#include <hip/hip_runtime.h>

#define IN_F 512
#define OUT_F 768
#define BD 256   // discrimination features (blocks)
#define ID 16    // intermediate dim
#define ND 256   // batch

// One block per b. 256 threads, thread n owns output row element out[n, 512+b].
__global__ __launch_bounds__(256) void mbd_kernel(const float* __restrict__ x,
                                                  const float* __restrict__ T,
                                                  float* __restrict__ out) {
    __shared__ float Tl[IN_F * ID];  // 32 KB; reused for M (16 KB) in phase 2
    const int b = blockIdx.x;
    const int t = threadIdx.x;

    // ---- stage T[:, b, :] (512 x 16 fp32 = 32 KB) into LDS ----
    {
        const float* Tb = T + (size_t)b * ID;
        // 2048 float4 chunks; thread k loads chunk k, k+256, ...
        for (int k = t; k < (IN_F * ID) / 4; k += 256) {
            int f = k >> 2;            // 0..511
            int e = (k & 3) << 2;      // 0,4,8,12
            float4 v = *reinterpret_cast<const float4*>(Tb + (size_t)f * (BD * ID) + e);
            *reinterpret_cast<float4*>(&Tl[f * ID + e]) = v;
        }
    }
    __syncthreads();

    // ---- phase 1: m[i] = sum_f x[n,f] * T[f,b,i]  (16 indep accumulators) ----
    const int n = t;
    float m[ID];
#pragma unroll
    for (int i = 0; i < ID; ++i) m[i] = 0.f;

    const float4* xr = reinterpret_cast<const float4*>(x + (size_t)n * IN_F);
    for (int f4 = 0; f4 < IN_F / 4; ++f4) {
        float4 xv = xr[f4];
        const float* tp = &Tl[(f4 * 4) * ID];
#pragma unroll
        for (int i = 0; i < ID; ++i) m[i] = fmaf(xv.x, tp[i], m[i]);
#pragma unroll
        for (int i = 0; i < ID; ++i) m[i] = fmaf(xv.y, tp[ID + i], m[i]);
#pragma unroll
        for (int i = 0; i < ID; ++i) m[i] = fmaf(xv.z, tp[2 * ID + i], m[i]);
#pragma unroll
        for (int i = 0; i < ID; ++i) m[i] = fmaf(xv.w, tp[3 * ID + i], m[i]);
    }

    __syncthreads();  // everyone done reading Tl
    // ---- publish M[:, b, :] into (reused) LDS ----
    float* Ml = Tl;
#pragma unroll
    for (int i = 0; i < ID; i += 4) {
        float4 v = make_float4(m[i], m[i + 1], m[i + 2], m[i + 3]);
        *reinterpret_cast<float4*>(&Ml[n * ID + i]) = v;
    }
    __syncthreads();

    // ---- phase 2: acc = sum_j exp(-sum_i |m[i] - M[j,i]|) ----
    float acc = 0.f;
    for (int j = 0; j < ND; ++j) {
        const float* mj = &Ml[j * ID];  // wave-uniform address -> LDS broadcast
        float s0 = 0.f, s1 = 0.f, s2 = 0.f, s3 = 0.f;
#pragma unroll
        for (int i = 0; i < ID; i += 4) {
            s0 += fabsf(m[i + 0] - mj[i + 0]);
            s1 += fabsf(m[i + 1] - mj[i + 1]);
            s2 += fabsf(m[i + 2] - mj[i + 2]);
            s3 += fabsf(m[i + 3] - mj[i + 3]);
        }
        float l1 = (s0 + s1) + (s2 + s3);
        acc += __expf(-l1);
    }

    // out[n, 512 + b] = acc - 1 (self pair)
    out[(size_t)n * OUT_F + IN_F + b] = acc - 1.f;

    // ---- concat: block b copies x row b -> out[b, 0:512] ----
    {
        const float4* xs = reinterpret_cast<const float4*>(x + (size_t)b * IN_F);
        float4* od = reinterpret_cast<float4*>(out + (size_t)b * OUT_F);
        for (int k = t; k < IN_F / 4; k += 256) od[k] = xs[k];
    }
}

extern "C" void kernel_launch(void* const* d_in, const int* in_sizes, int n_in,
                              void* d_out, int out_size, void* d_ws, size_t ws_size,
                              hipStream_t stream) {
    const float* x = (const float*)d_in[0];
    const float* T = (const float*)d_in[1];
    float* out = (float*)d_out;
    mbd_kernel<<<dim3(BD), dim3(256), 0, stream>>>(x, T, out);
}